// Round 11
// baseline (108.147 us; speedup 1.0000x reference)
//
#include <hip/hip_runtime.h>
#include <cstdint>

// BasisFunction1D: out[o,b] = sum_i (1-d)*P[idx,o,i] + d*P[idx+1,o,i]
//
// R17: ILP-first main_k (128 VGPR, 4 b/thread), barrier-free persistent slab.
//   Series: R10 (32w, VGPR32) 38us; R15 (16w, VGPR64) 53; R16 (32w, VGPR64)
//   45 -- barrier-free + clean traffic + occupancy all exhausted, yet 4x
//   above the ~8us component model => dependent-latency stall. The never-
//   varied lever is VGPR budget: 32-64 regs cap outstanding ds_read_b128 at
//   ~2-3/wave. R17: launch_bounds(512,4) -> 128 VGPR, each thread owns 4 b
//   -> 4 independent gathers + 16 fdot2 chains per i, unrolled over 32 i.
//   Grid 512 = 32 s x (iq*4+bq); xcd=pair&7 -> two 256KB T-windows per XCD.
//   4-way i-split partials + reduce (proven cheap, no RMW).

#define NG 128
#define NI 128
#define NO 128
#define NB 8192

using half2v  = __attribute__((ext_vector_type(2))) _Float16;
using float4v = __attribute__((ext_vector_type(4))) float;

__device__ inline uint32_t pack_f16x2(float lo, float hi) {
    _Float16 hl = (_Float16)lo, hh = (_Float16)hi;
    return (uint32_t)__builtin_bit_cast(unsigned short, hl) |
           ((uint32_t)__builtin_bit_cast(unsigned short, hh) << 16);
}

__device__ inline void load_lds16(const uint32_t* g, uint32_t* l) {
    __builtin_amdgcn_global_load_lds(
        (const __attribute__((address_space(1))) uint32_t*)g,
        (__attribute__((address_space(3))) uint32_t*)l, 16, 0, 0);
}

// ---- K1: P[g,o,i] -> Q2[((s*NI+i)*NG+g)*4+ow] = pack(P, dP), o=s*4+ow ----
// (proven R10 version: 64B-contiguous stores)
__global__ __launch_bounds__(256) void build_q(const float* __restrict__ P,
                                               uint32_t* __restrict__ Q2) {
    __shared__ float L[5][16][128];             // 40 KB
    const int gb = blockIdx.x >> 3;
    const int ob = blockIdx.x & 7;
    const int g0 = gb * 4;
    const int o0 = ob * 16;
    const int s0 = ob * 4;
    const int t  = threadIdx.x;
    #pragma unroll
    for (int pass = 0; pass < 40; ++pass) {     // 80 rows x 128 i
        int row = pass * 2 + (t >> 7);
        int i   = t & 127;
        int gg  = row >> 4, ol = row & 15;
        L[gg][ol][i] = P[(size_t)(g0 + gg) * (NO * NI) + (o0 + ol) * NI + i];
    }
    __syncthreads();
    #pragma unroll
    for (int pp = 0; pp < 2; ++pp) {
        int item = pp * 256 + t;                // 4 sl x 128 i
        int i  = item & 127;
        int sl = item >> 7;
        uint32_t* dst = Q2 + ((size_t)((s0 + sl) * NI + i) * NG + g0) * 4;
        #pragma unroll
        for (int gg = 0; gg < 4; ++gg) {
            uint32_t r[4];
            #pragma unroll
            for (int ow = 0; ow < 4; ++ow) {
                float pl = L[gg][sl * 4 + ow][i];
                float dd = L[gg + 1][sl * 4 + ow][i] - pl;
                r[ow] = pack_f16x2(pl, dd);
            }
            *(uint4*)(dst + gg * 4) = make_uint4(r[0], r[1], r[2], r[3]);
        }
    }
}

// ---- K2: bucketize x -> T[i][b] = (idx*16) | (f16(d) << 16) (coalesced) --
__global__ __launch_bounds__(256) void build_t(const float* __restrict__ x,
                                               const float* __restrict__ borders,
                                               const float* __restrict__ icl,
                                               uint32_t* __restrict__ T) {
    const int e0 = (blockIdx.x * 256 + threadIdx.x) * 4;
    const float4 xv = *(const float4*)(x + e0);
    uint32_t r[4];
    const float xs[4] = {xv.x, xv.y, xv.z, xv.w};
    #pragma unroll
    for (int k = 0; k < 4; ++k) {
        float v = xs[k];
        float ea = __expf(-fabsf(v));
        float cdf = v > 0.f ? 1.f - 0.5f * ea : 0.5f * ea;
        int idx = (int)(cdf * 128.f);
        idx = idx > 127 ? 127 : idx;
        float d = (v - borders[idx]) * icl[idx];
        _Float16 hd = (_Float16)d;
        r[k] = ((uint32_t)idx << 4) |
               ((uint32_t)__builtin_bit_cast(unsigned short, hd) << 16);
    }
    *(uint4*)(T + e0) = make_uint4(r[0], r[1], r[2], r[3]);
}

// ---- K3: main. 512 thr; 64KB slab; 4 b/thread x 4 o x 32 i; 128 VGPR -----
// Barrier-free main loop; ILP: 4 independent gathers + 16 fdot2 chains per i.
__global__ __launch_bounds__(512, 4) void main_k(const uint32_t* __restrict__ Q2,
                                                 const uint32_t* __restrict__ T,
                                                 float* __restrict__ part) {
    __shared__ __align__(16) uint32_t slab[32 * NG * 4];   // 64 KB
    const int t    = threadIdx.x;
    const int bx   = blockIdx.x;
    const int pair = bx & 15;                   // iq*4+bq; xcd = pair&7
    const int s    = bx >> 4;                   // o-slice (4 o)
    const int iq   = pair >> 2;                 // i-quarter (32 i)
    const int bq   = pair & 3;                  // b-quarter (2048 b)
    const int b0   = (bq << 11) | t;            // + {0,512,1024,1536}
    const uint32_t* Qs = Q2 + ((size_t)s * NI + iq * 32) * (NG * 4);
    const uint32_t* Tb = T + (size_t)(iq * 32) * NB + b0;

    // one-time stage: 32i x 128g x 4o panel (64 KB; 8 x gll16/thread)
    #pragma unroll
    for (int k = 0; k < 8; ++k)
        load_lds16(Qs + (size_t)(t + k * 512) * 4, &slab[(t + k * 512) * 4]);
    // T(i=0) for this thread's 4 b's (issued under the stage drain)
    uint32_t tw0 = Tb[0], tw1 = Tb[512], tw2 = Tb[1024], tw3 = Tb[1536];
    __syncthreads();                            // ONLY barrier in the kernel

    float acc[16];
    #pragma unroll
    for (int k = 0; k < 16; ++k) acc[k] = 0.f;

    #pragma unroll
    for (int i = 0; i < 32; ++i) {
        uint32_t nw0, nw1, nw2, nw3;
        if (i < 31) {                           // prefetch T(i+1)
            const uint32_t* tn = Tb + (size_t)(i + 1) * NB;
            nw0 = tn[0]; nw1 = tn[512]; nw2 = tn[1024]; nw3 = tn[1536];
        }
        const char* sp = (const char*)slab + i * 2048;
        const uint32_t tws[4] = {tw0, tw1, tw2, tw3};
        #pragma unroll
        for (int j = 0; j < 4; ++j) {           // 4 independent gathers
            uint32_t tw  = tws[j];
            uint4 q = *(const uint4*)(sp + (tw & 0xFFFFu));     // idx*16
            uint32_t w2b = (tw & 0xFFFF0000u) | 0x3C00u;        // {1.0h, d}
            half2v w2 = __builtin_bit_cast(half2v, w2b);
            acc[j * 4 + 0] = __builtin_amdgcn_fdot2(
                __builtin_bit_cast(half2v, q.x), w2, acc[j * 4 + 0], false);
            acc[j * 4 + 1] = __builtin_amdgcn_fdot2(
                __builtin_bit_cast(half2v, q.y), w2, acc[j * 4 + 1], false);
            acc[j * 4 + 2] = __builtin_amdgcn_fdot2(
                __builtin_bit_cast(half2v, q.z), w2, acc[j * 4 + 2], false);
            acc[j * 4 + 3] = __builtin_amdgcn_fdot2(
                __builtin_bit_cast(half2v, q.w), w2, acc[j * 4 + 3], false);
        }
        if (i < 31) { tw0 = nw0; tw1 = nw1; tw2 = nw2; tw3 = nw3; }
    }

    // partials part[iq][o][b]: coalesced 2KB runs per (o, b-slot)
    float* po = part + (size_t)iq * (NO * NB) + (size_t)(s * 4) * NB;
    #pragma unroll
    for (int j = 0; j < 4; ++j)
        #pragma unroll
        for (int ow = 0; ow < 4; ++ow)
            po[(size_t)ow * NB + b0 + j * 512] = acc[j * 4 + ow];
}

// ---- K4: out = part0+part1+part2+part3 (1M floats) ----
__global__ __launch_bounds__(256) void reduce_k(const float* __restrict__ part,
                                                float* __restrict__ out) {
    const int e0 = (blockIdx.x * 256 + threadIdx.x) * 4;
    const size_t st = (size_t)NO * NB;
    const float4v v0 = *(const float4v*)(part + e0);
    const float4v v1 = *(const float4v*)(part + st + e0);
    const float4v v2 = *(const float4v*)(part + 2 * st + e0);
    const float4v v3 = *(const float4v*)(part + 3 * st + e0);
    const float4v r  = (v0 + v1) + (v2 + v3);
    __builtin_nontemporal_store(r, (float4v*)(out + e0));
}

extern "C" void kernel_launch(void* const* d_in, const int* in_sizes, int n_in,
                              void* d_out, int out_size, void* d_ws, size_t ws_size,
                              hipStream_t stream) {
    const float* x       = (const float*)d_in[0];
    const float* P       = (const float*)d_in[1];
    const float* borders = (const float*)d_in[2];
    const float* icl     = (const float*)d_in[3];
    float* out = (float*)d_out;

    uint32_t* Q2  = (uint32_t*)d_ws;                 // 8 MB
    uint32_t* T   = Q2 + (size_t)NO * NI * NG;       // 4 MB
    float*    prt = (float*)(T + (size_t)NI * NB);   // 16 MB (four quarters)

    hipLaunchKernelGGL(build_q, dim3(256), dim3(256), 0, stream, P, Q2);
    hipLaunchKernelGGL(build_t, dim3(NI * NB / 1024), dim3(256), 0, stream,
                       x, borders, icl, T);
    hipLaunchKernelGGL(main_k, dim3(512), dim3(512), 0, stream, Q2, T, prt);
    hipLaunchKernelGGL(reduce_k, dim3(NO * NB / 1024), dim3(256), 0, stream,
                       prt, out);
}